// Round 1
// baseline (193.963 us; speedup 1.0000x reference)
//
#include <hip/hip_runtime.h>
#include <stdint.h>

#define NB 2
#define NS 2048
#define NHQ 32
#define NHK 8
#define NG 4
#define ND 128
#define NWIN 1024

using bf16x8 = __bf16 __attribute__((ext_vector_type(8)));
using f32x4  = float  __attribute__((ext_vector_type(4)));
using f32x2  = float  __attribute__((ext_vector_type(2)));
using f32x8  = float  __attribute__((ext_vector_type(8)));
using u16x4  = unsigned short __attribute__((ext_vector_type(4)));
using u16x8  = unsigned short __attribute__((ext_vector_type(8)));

static __device__ __forceinline__ unsigned short f2bf(float x) {
  unsigned int u = __builtin_bit_cast(unsigned int, x);
  u += 0x7FFFu + ((u >> 16) & 1u);
  return (unsigned short)(u >> 16);
}

#define L2_10K (13.287712379549449f / 64.0f)  // log2(10000)/64

// DPP row_ror reduction within 16-lane rows (keeps reductions off the LDS pipe)
#define ROR(x, N) __builtin_bit_cast(float, __builtin_amdgcn_mov_dpp( \
    __builtin_bit_cast(int, (x)), 0x120 + (N), 0xF, 0xF, false))

// ---------------- pre-pass: rope K, convert K/V to bf16 ----------------
__global__ __launch_bounds__(256) void rope_kv(
    const float* __restrict__ kin, const float* __restrict__ vin,
    const int* __restrict__ pos,
    unsigned short* __restrict__ kb, unsigned short* __restrict__ vb) {
  const int tok = blockIdx.x;
  const int t = threadIdx.x;
  const int b = tok >> 11, j = tok & (NS - 1);
  __shared__ float csh[128];
  if (t < 64) {
    float s, c;
    __sincosf((float)pos[tok] * exp2f(-(float)t * L2_10K), &s, &c);
    csh[t] = c;
    csh[64 + t] = s;
  }
  __syncthreads();
  const int hk = t >> 5;
  const int dr = (t & 31) << 2;
  const int f = dr & 63;
  const float* kp = kin + (size_t)tok * (NHK * ND) + hk * ND;
  f32x4 a = *(const f32x4*)(kp + dr);
  f32x4 p = *(const f32x4*)(kp + (dr ^ 64));
  u16x4 uo;
#pragma unroll
  for (int i = 0; i < 4; ++i) {
    float c = csh[f + i], s = csh[64 + f + i];
    float val = (dr < 64) ? (a[i] * c - p[i] * s) : (a[i] * c + p[i] * s);
    uo[i] = f2bf(val);
  }
  const size_t ko = ((size_t)(b * NHK + hk) * NS + j) * ND + dr;
  *(u16x4*)(kb + ko) = uo;
  const float* vp = vin + (size_t)tok * (NHK * ND) + hk * ND;
  f32x4 av = *(const f32x4*)(vp + dr);
  u16x4 vo;
#pragma unroll
  for (int i = 0; i < 4; ++i) vo[i] = f2bf(av[i]);
  *(u16x4*)(vb + ko) = vo;
}

// ---------------- fused flash attention ----------------
// block: 512 thr = 8 waves = (qsub 0/1) x (g 0..3); block owns (b, hk, 32 q rows)
// wave: 16 q rows x D=128, KV tiles of 32, mfma 16x16x32 bf16
template <bool PRE>
__global__ __launch_bounds__(512, 4) void attn_fwd(
    const float* __restrict__ qin, const float* __restrict__ kin,
    const float* __restrict__ vin, const int* __restrict__ pos,
    const unsigned short* __restrict__ kb, const unsigned short* __restrict__ vb,
    float* __restrict__ out) {
  __shared__ __align__(16) unsigned short Klds[32 * 128];   // row-major, XOR swizzled
  __shared__ __align__(16) unsigned short Vt[128 * 44];     // transposed, stride 44 u16 (88B)
  __shared__ __align__(16) unsigned short Plds[8][16 * 40]; // per-wave P, stride 40 u16 (80B)

  const int bid = blockIdx.x;
  const int qt = bid & 63;
  const int hk = (bid >> 6) & 7;
  const int b = bid >> 9;
  const int tid = threadIdx.x;
  const int w = tid >> 6;
  const int lane = tid & 63;
  const int h = lane >> 4;
  const int ln = lane & 15;
  const int g = w & 3;
  const int q0b = qt << 5;
  const int q0 = q0b + ((w >> 2) << 4);

  // ---- Q fragments: rope + scale*log2e, bf16 ----
  const int qrow = q0 + ln;
  const size_t tokq = (size_t)b * NS + qrow;
  const float* qp = qin + tokq * (NHQ * ND) + (hk * NG + g) * ND;
  const int posq = pos[tokq];
  const float QSC = 0.08838834764831845f * 1.4426950408889634f;
  bf16x8 qfr[4];
  {
    const int r0 = h << 3;
    const int r1 = 32 + (h << 3);
    f32x8 a0 = *(const f32x8*)(qp + r0);
    f32x8 a1 = *(const f32x8*)(qp + r1);
    f32x8 a2 = *(const f32x8*)(qp + r0 + 64);
    f32x8 a3 = *(const f32x8*)(qp + r1 + 64);
    u16x8 u0, u1, u2, u3;
#pragma unroll
    for (int i = 0; i < 8; ++i) {
      float c0, s0, c1, s1;
      __sincosf((float)posq * exp2f(-(float)(r0 + i) * L2_10K), &s0, &c0);
      __sincosf((float)posq * exp2f(-(float)(r1 + i) * L2_10K), &s1, &c1);
      u0[i] = f2bf((a0[i] * c0 - a2[i] * s0) * QSC);
      u1[i] = f2bf((a1[i] * c1 - a3[i] * s1) * QSC);
      u2[i] = f2bf((a2[i] * c0 + a0[i] * s0) * QSC);
      u3[i] = f2bf((a3[i] * c1 + a1[i] * s1) * QSC);
    }
    qfr[0] = __builtin_bit_cast(bf16x8, u0);
    qfr[1] = __builtin_bit_cast(bf16x8, u1);
    qfr[2] = __builtin_bit_cast(bf16x8, u2);
    qfr[3] = __builtin_bit_cast(bf16x8, u3);
  }

  f32x4 Oc[8] = {};
  float m[4] = {-3.0e38f, -3.0e38f, -3.0e38f, -3.0e38f};
  float lsum[4] = {};

  int lo = q0b - (NWIN - 1);
  if (lo < 0) lo = 0;
  lo &= ~31;

  char* KB = (char*)Klds;
  char* VB = (char*)Vt;
  unsigned short* pw = Plds[w];

  for (int j0 = lo; j0 <= q0b + 31; j0 += 32) {
    __syncthreads();
    // ---- stage K tile (32 x 128 bf16), XOR swizzle ((j&7)<<4) ----
    {
      const int j = tid >> 4;
      const int dr = (tid & 15) << 3;
      const int off = ((j << 8) + (dr << 1)) ^ ((j & 7) << 4);
      if (PRE) {
        const unsigned short* src =
            kb + ((size_t)(b * NHK + hk) * NS + (j0 + j)) * ND + dr;
        *(u16x8*)(KB + off) = *(const u16x8*)src;
      } else {
        const float* kp = kin + (size_t)(b * NS + j0 + j) * (NHK * ND) + hk * ND;
        f32x8 a = *(const f32x8*)(kp + dr);
        f32x8 p = *(const f32x8*)(kp + (dr ^ 64));
        const int f = dr & 63;
        const int pj = pos[b * NS + j0 + j];
        u16x8 uo;
#pragma unroll
        for (int i = 0; i < 8; ++i) {
          float s, c;
          __sincosf((float)pj * exp2f(-(float)(f + i) * L2_10K), &s, &c);
          float val = (dr < 64) ? (a[i] * c - p[i] * s) : (a[i] * c + p[i] * s);
          uo[i] = f2bf(val);
        }
        *(u16x8*)(KB + off) = uo;
      }
    }
    // ---- stage V tile transposed: Vt[d][j], stride 88B ----
    {
      const int d = (tid & 63) << 1;
      const int j4 = (tid >> 6) << 2;
      u16x4 w0, w1;
      if (PRE) {
        const unsigned short* vs =
            vb + ((size_t)(b * NHK + hk) * NS + (j0 + j4)) * ND + d;
#pragma unroll
        for (int jj = 0; jj < 4; ++jj) {
          unsigned int rv = *(const unsigned int*)(vs + (size_t)jj * ND);
          w0[jj] = (unsigned short)(rv & 0xFFFFu);
          w1[jj] = (unsigned short)(rv >> 16);
        }
      } else {
        const float* vp =
            vin + (size_t)(b * NS + j0 + j4) * (NHK * ND) + hk * ND + d;
#pragma unroll
        for (int jj = 0; jj < 4; ++jj) {
          f32x2 rv = *(const f32x2*)(vp + (size_t)jj * (NHK * ND));
          w0[jj] = f2bf(rv[0]);
          w1[jj] = f2bf(rv[1]);
        }
      }
      *(u16x4*)(VB + (size_t)d * 88 + (j4 << 1)) = w0;
      *(u16x4*)(VB + (size_t)(d + 1) * 88 + (j4 << 1)) = w1;
    }
    __syncthreads();

    // ---- S = Q K^T (two 16x16 key tiles) ----
    f32x4 s0 = {}, s1 = {};
#pragma unroll
    for (int c = 0; c < 4; ++c) {
      bf16x8 k0 = *(const bf16x8*)(
          KB + (((ln << 8) + (c << 6) + (h << 4)) ^ ((ln & 7) << 4)));
      bf16x8 k1 = *(const bf16x8*)(
          KB + ((((16 + ln) << 8) + (c << 6) + (h << 4)) ^ ((ln & 7) << 4)));
      s0 = __builtin_amdgcn_mfma_f32_16x16x32_bf16(qfr[c], k0, s0, 0, 0, 0);
      s1 = __builtin_amdgcn_mfma_f32_16x16x32_bf16(qfr[c], k1, s1, 0, 0, 0);
    }

    // ---- mask + online softmax (exp2 domain, DPP row reductions) ----
    const int jc = j0 + ln;
    float corr[4], p0v[4], p1v[4];
#pragma unroll
    for (int r = 0; r < 4; ++r) {
      const int irow = q0 + (h << 2) + r;
      float v0 = (jc <= irow && irow - jc < NWIN) ? s0[r] : -__builtin_inff();
      float v1 = (jc + 16 <= irow && irow - (jc + 16) < NWIN) ? s1[r]
                                                              : -__builtin_inff();
      float tm = fmaxf(v0, v1);
      tm = fmaxf(tm, ROR(tm, 1));
      tm = fmaxf(tm, ROR(tm, 2));
      tm = fmaxf(tm, ROR(tm, 4));
      tm = fmaxf(tm, ROR(tm, 8));
      const float mn = fmaxf(m[r], tm);
      const float co = exp2f(m[r] - mn);
      m[r] = mn;
      const float e0 = exp2f(v0 - mn);
      const float e1 = exp2f(v1 - mn);
      float rs = e0 + e1;
      rs += ROR(rs, 1);
      rs += ROR(rs, 2);
      rs += ROR(rs, 4);
      rs += ROR(rs, 8);
      lsum[r] = lsum[r] * co + rs;
      corr[r] = co;
      p0v[r] = e0;
      p1v[r] = e1;
    }
#pragma unroll
    for (int dblk = 0; dblk < 8; ++dblk)
#pragma unroll
      for (int r = 0; r < 4; ++r) Oc[dblk][r] *= corr[r];

    // ---- P -> bf16 via wave-private LDS roundtrip ----
#pragma unroll
    for (int r = 0; r < 4; ++r) {
      pw[((h << 2) + r) * 40 + ln] = f2bf(p0v[r]);
      pw[((h << 2) + r) * 40 + 16 + ln] = f2bf(p1v[r]);
    }
    asm volatile("s_waitcnt lgkmcnt(0)" ::: "memory");
    const bf16x8 pa = *(const bf16x8*)((const char*)pw + ln * 80 + (h << 4));
#pragma unroll
    for (int dblk = 0; dblk < 8; ++dblk) {
      const char* vbase = VB + (size_t)(dblk * 16 + ln) * 88 + (h << 4);
      u16x4 vlo = *(const u16x4*)vbase;
      u16x4 vhi = *(const u16x4*)(vbase + 8);
      bf16x8 vv = __builtin_bit_cast(
          bf16x8, __builtin_shufflevector(vlo, vhi, 0, 1, 2, 3, 4, 5, 6, 7));
      Oc[dblk] = __builtin_amdgcn_mfma_f32_16x16x32_bf16(pa, vv, Oc[dblk], 0, 0, 0);
    }
  }

  // ---- epilogue: O / lsum ----
#pragma unroll
  for (int r = 0; r < 4; ++r) {
    const float rl = 1.0f / lsum[r];
    const int irow = q0 + (h << 2) + r;
    float* op = out + ((size_t)b * NS + irow) * (NHQ * ND) + (hk * NG + g) * ND + ln;
#pragma unroll
    for (int dblk = 0; dblk < 8; ++dblk) op[dblk * 16] = Oc[dblk][r] * rl;
  }
}

extern "C" void kernel_launch(void* const* d_in, const int* in_sizes, int n_in,
                              void* d_out, int out_size, void* d_ws, size_t ws_size,
                              hipStream_t stream) {
  const float* q = (const float*)d_in[0];
  const float* k = (const float*)d_in[1];
  const float* v = (const float*)d_in[2];
  const int* pos = (const int*)d_in[3];
  float* out = (float*)d_out;

  const size_t nkv = (size_t)NB * NHK * NS * ND;  // elements per K/V bf16 buffer
  const size_t need = 2 * nkv * sizeof(unsigned short);
  const int grid = NB * NHK * (NS / 32);  // 1024 blocks

  if (ws_size >= need) {
    unsigned short* kb = (unsigned short*)d_ws;
    unsigned short* vb = kb + nkv;
    rope_kv<<<NB * NS, 256, 0, stream>>>(k, v, pos, kb, vb);
    attn_fwd<true><<<grid, 512, 0, stream>>>(q, k, v, pos, kb, vb, out);
  } else {
    attn_fwd<false><<<grid, 512, 0, stream>>>(q, k, v, pos, nullptr, nullptr, out);
  }
}

// Round 3
// 112.423 us; speedup vs baseline: 1.7253x; 1.7253x over previous
//
#include <hip/hip_runtime.h>
#include <stdint.h>

#define NB 2
#define NS 2048
#define NHK 8
#define ND 128
#define NWIN 1024

using bf16x8 = __bf16 __attribute__((ext_vector_type(8)));
using f32x4  = float  __attribute__((ext_vector_type(4)));
using f32x8  = float  __attribute__((ext_vector_type(8)));
using u16x8  = unsigned short __attribute__((ext_vector_type(8)));
using u32x4  = unsigned int   __attribute__((ext_vector_type(4)));

#define L2_10K (13.287712379549449f / 64.0f)  // log2(10000)/64
#define MASKV (-3.0e38f)

static __device__ __forceinline__ float ex2(float x) {
  return __builtin_amdgcn_exp2f(x);
}

static __device__ __forceinline__ unsigned short f2bf(float x) {
  unsigned int u = __builtin_bit_cast(unsigned int, x);
  u += 0x7FFFu + ((u >> 16) & 1u);
  return (unsigned short)(u >> 16);
}

// pack two f32 -> (bf16 lo, bf16 hi) in one u32
static __device__ __forceinline__ unsigned int cvtpk(float lo, float hi) {
  unsigned int r;
  asm("v_cvt_pk_bf16_f32 %0, %1, %2" : "=v"(r) : "v"(lo), "v"(hi));
  return r;
}

// async global->LDS, 16B per lane, LDS dest = uniform base + lane*16
static __device__ __forceinline__ void gll16(const void* g, void* l) {
  __builtin_amdgcn_global_load_lds(
      (const __attribute__((address_space(1))) void*)g,
      (__attribute__((address_space(3))) void*)l, 16, 0, 0);
}

// DPP row_ror reduction within 16-lane rows
#define ROR(x, N) __builtin_bit_cast(float, __builtin_amdgcn_mov_dpp( \
    __builtin_bit_cast(int, (x)), 0x120 + (N), 0xF, 0xF, false))

// ---------------- cos/sin table: tab[p][0..63]=cos, [64..127]=sin ----------------
__global__ __launch_bounds__(64) void build_tab(float* __restrict__ tab) {
  const int p = blockIdx.x, f = threadIdx.x;
  float s, c;
  __sincosf((float)p * ex2(-(float)f * L2_10K), &s, &c);
  tab[(size_t)p * 128 + f] = c;
  tab[(size_t)p * 128 + 64 + f] = s;
}

// ---------------- prepass: build per-tile K (roped, swizzled) and V (pair) images ----
// grid 1024 = (b,hk,tile32); K image 8192B: unit u(0..511): row j=u>>4,
//   16B at ((u&15)*16 ^ ((j&7)<<4)); V image 2048 u32 [d][jp] stride16:
//   u32 = (bf16 V[j0+jp][d], bf16 V[j0+jp+16][d])
__global__ __launch_bounds__(256) void prepass(
    const float* __restrict__ kin, const float* __restrict__ vin,
    const int* __restrict__ pos, const float* __restrict__ tab,
    unsigned short* __restrict__ kimg, unsigned int* __restrict__ vimg) {
  const int bid = blockIdx.x;
  const int ti = bid & 63, gidx = bid >> 6;
  const int hk = gidx & 7, b = gidx >> 3;
  const int t = threadIdx.x;

  unsigned short* kout = kimg + (size_t)bid * 4096;
#pragma unroll
  for (int uu = 0; uu < 2; ++uu) {
    const int u = t * 2 + uu;
    const int j = u >> 4;
    const int d0 = ((u & 15) << 3) ^ ((j & 7) << 3);  // u16 index
    const int tok = (b << 11) + (ti << 5) + j;
    const float* kp = kin + (size_t)tok * (NHK * ND) + hk * ND;
    f32x8 a = *(const f32x8*)(kp + d0);
    f32x8 p = *(const f32x8*)(kp + (d0 ^ 64));
    const float* tr = tab + (size_t)(pos[tok] & 2047) * 128 + (d0 & 63);
    f32x8 c8 = *(const f32x8*)tr;
    f32x8 s8 = *(const f32x8*)(tr + 64);
    u16x8 o;
#pragma unroll
    for (int i = 0; i < 8; ++i) {
      float val = (d0 < 64) ? (a[i] * c8[i] - p[i] * s8[i])
                            : (a[i] * c8[i] + p[i] * s8[i]);
      o[i] = f2bf(val);
    }
    *(u16x8*)(kout + (size_t)u * 8) = o;
  }

  unsigned int* vout = vimg + (size_t)bid * 2048;
  {
    const int d = t >> 1;
    const int jp0 = (t & 1) << 3;
    const float* vp = vin + (size_t)((b << 11) + (ti << 5)) * (NHK * ND) + hk * ND + d;
    unsigned int o[8];
#pragma unroll
    for (int i = 0; i < 8; ++i)
      o[i] = cvtpk(vp[(size_t)(jp0 + i) * (NHK * ND)],
                   vp[(size_t)(jp0 + i + 16) * (NHK * ND)]);
    u32x4 w0 = {o[0], o[1], o[2], o[3]};
    u32x4 w1 = {o[4], o[5], o[6], o[7]};
    *(u32x4*)(vout + d * 16 + jp0) = w0;
    *(u32x4*)(vout + d * 16 + jp0 + 4) = w1;
  }
}

// ---------------- fused flash attention ----------------
// 256 thr = 4 waves (one per g). Wave owns 32 q-rows (2 halves of 16) x D=128.
// KV tiles of 32; double-buffered LDS staged via global_load_lds from images.
template <bool PRE>
__global__ __launch_bounds__(256, 2) void attn_fwd(
    const float* __restrict__ qin, const float* __restrict__ kin,
    const float* __restrict__ vin, const int* __restrict__ pos,
    const char* __restrict__ kimg, const char* __restrict__ vimg,
    float* __restrict__ out) {
  __shared__ __align__(16) char Kb[2][8192];
  __shared__ __align__(16) char Vb[2][8192];
  __shared__ __align__(16) unsigned int Pw[4][32 * 20];

  const int B = blockIdx.x;
  // XCD swizzle: all 64 q-tiles of a (b,hk) group land on one XCD; heavy tiles first
  const int group = (B & 7) + ((B >> 9) << 3);
  const int qt = 63 - ((B >> 3) & 63);
  const int hk = group & 7, b = group >> 3;

  const int tid = threadIdx.x;
  const int w = tid >> 6, lane = tid & 63, h = lane >> 4, ln = lane & 15;
  const int g = w;
  const int q0b = qt << 5;
  int lo = q0b - (NWIN - 1);
  if (lo < 0) lo = 0;
  lo &= ~31;
  const int ti0 = lo >> 5;
  const int nt = (q0b >> 5) - ti0 + 1;

  const size_t gbase = (size_t)group * 64 * 8192;
  const char* kg = PRE ? kimg + gbase + (size_t)(w * 128 + lane) * 16 : nullptr;
  const char* vg = PRE ? vimg + gbase + (size_t)(w * 128 + lane) * 16 : nullptr;

  auto stage = [&](int cur, int ti) {
    if constexpr (PRE) {
      const char* ks = kg + (size_t)ti * 8192;
      const char* vs = vg + (size_t)ti * 8192;
      char* kd = &Kb[cur][w * 2048];
      char* vd = &Vb[cur][w * 2048];
      gll16(ks, kd);
      gll16(ks + 1024, kd + 1024);
      gll16(vs, vd);
      gll16(vs + 1024, vd + 1024);
    } else {
      // K: rope inline, swizzled writes
      const int j = tid >> 3;
      const int du = (tid & 7) << 4;
      const int tok = (b << 11) + (ti << 5) + j;
      const float* kp = kin + (size_t)tok * (NHK * ND) + hk * ND;
      const float pj = (float)pos[tok];
#pragma unroll
      for (int gq = 0; gq < 2; ++gq) {
        const int dd = du + gq * 8;
        f32x8 a = *(const f32x8*)(kp + dd);
        f32x8 p = *(const f32x8*)(kp + (dd ^ 64));
        u16x8 o;
#pragma unroll
        for (int i = 0; i < 8; ++i) {
          float s, c;
          __sincosf(pj * ex2(-(float)((dd & 63) + i) * L2_10K), &s, &c);
          float val = (dd < 64) ? (a[i] * c - p[i] * s) : (a[i] * c + p[i] * s);
          o[i] = f2bf(val);
        }
        *(u16x8*)(&Kb[cur][((j << 8) + (dd << 1)) ^ ((j & 7) << 4)]) = o;
      }
      // V: pair-interleaved
      const int d = tid >> 1;
      const int jp0 = (tid & 1) << 3;
      const float* vp = vin + (size_t)((b << 11) + (ti << 5)) * (NHK * ND) + hk * ND + d;
      unsigned int o[8];
#pragma unroll
      for (int i = 0; i < 8; ++i)
        o[i] = cvtpk(vp[(size_t)(jp0 + i) * (NHK * ND)],
                     vp[(size_t)(jp0 + i + 16) * (NHK * ND)]);
      unsigned int* vb32 = (unsigned int*)Vb[cur];
      u32x4 w0 = {o[0], o[1], o[2], o[3]};
      u32x4 w1 = {o[4], o[5], o[6], o[7]};
      *(u32x4*)(vb32 + d * 16 + jp0) = w0;
      *(u32x4*)(vb32 + d * 16 + jp0 + 4) = w1;
    }
  };

  // prologue: stage tile 0 into buf0 (overlaps Q rope)
  stage(0, ti0);

  // ---- Q fragments: rope + scale*log2e, bf16 ----
  const float QSC = 0.08838834764831845f * 1.4426950408889634f;
  bf16x8 qfr[2][4];
#pragma unroll
  for (int hf = 0; hf < 2; ++hf) {
    const int qrow = q0b + hf * 16 + ln;
    const size_t tokq = (size_t)(b << 11) + qrow;
    const float* qp = qin + tokq * 4096 + (hk * 4 + g) * 128;
    const float posq = (float)pos[tokq];
    const int r0 = h << 3;
    const int r1 = 32 + (h << 3);
    f32x8 a0 = *(const f32x8*)(qp + r0);
    f32x8 a1 = *(const f32x8*)(qp + r1);
    f32x8 a2 = *(const f32x8*)(qp + r0 + 64);
    f32x8 a3 = *(const f32x8*)(qp + r1 + 64);
    u16x8 u0, u1, u2, u3;
#pragma unroll
    for (int i = 0; i < 8; ++i) {
      float c0, s0, c1, s1;
      __sincosf(posq * ex2(-(float)(r0 + i) * L2_10K), &s0, &c0);
      __sincosf(posq * ex2(-(float)(r1 + i) * L2_10K), &s1, &c1);
      u0[i] = f2bf((a0[i] * c0 - a2[i] * s0) * QSC);
      u1[i] = f2bf((a1[i] * c1 - a3[i] * s1) * QSC);
      u2[i] = f2bf((a2[i] * c0 + a0[i] * s0) * QSC);
      u3[i] = f2bf((a3[i] * c1 + a1[i] * s1) * QSC);
    }
    qfr[hf][0] = __builtin_bit_cast(bf16x8, u0);
    qfr[hf][1] = __builtin_bit_cast(bf16x8, u1);
    qfr[hf][2] = __builtin_bit_cast(bf16x8, u2);
    qfr[hf][3] = __builtin_bit_cast(bf16x8, u3);
  }

  f32x4 Oc[2][8] = {};
  float m[2][4] = {{-1e30f, -1e30f, -1e30f, -1e30f},
                   {-1e30f, -1e30f, -1e30f, -1e30f}};
  float lsum[2][4] = {};
  unsigned int* pw = Pw[w];
  const int sw = (ln & 7) << 4;

  for (int t = 0; t < nt; ++t) {
    const int cur = t & 1;
    asm volatile("s_waitcnt vmcnt(0)" ::: "memory");
    __syncthreads();  // tile-t data resident; prev reads of buf[cur^1] done
    if (t + 1 < nt) stage(cur ^ 1, ti0 + t + 1);

    const int j0 = (ti0 + t) << 5;
    const char* KB = Kb[cur];

    // ---- S = Q K^T (2 halves x 2 key sub-tiles) ----
    f32x4 sS[2][2] = {};
    __builtin_amdgcn_s_setprio(1);
#pragma unroll
    for (int c = 0; c < 4; ++c) {
      const bf16x8 k0 = *(const bf16x8*)(
          KB + (((ln << 8) + (c << 6) + (h << 4)) ^ sw));
      const bf16x8 k1 = *(const bf16x8*)(
          KB + ((((16 + ln) << 8) + (c << 6) + (h << 4)) ^ sw));
      sS[0][0] = __builtin_amdgcn_mfma_f32_16x16x32_bf16(qfr[0][c], k0, sS[0][0], 0, 0, 0);
      sS[0][1] = __builtin_amdgcn_mfma_f32_16x16x32_bf16(qfr[0][c], k1, sS[0][1], 0, 0, 0);
      sS[1][0] = __builtin_amdgcn_mfma_f32_16x16x32_bf16(qfr[1][c], k0, sS[1][0], 0, 0, 0);
      sS[1][1] = __builtin_amdgcn_mfma_f32_16x16x32_bf16(qfr[1][c], k1, sS[1][1], 0, 0, 0);
    }
    __builtin_amdgcn_s_setprio(0);

    // ---- mask only boundary tiles (wave-uniform branch) ----
    if ((j0 >= q0b) || (j0 < q0b - 992)) {
#pragma unroll
      for (int hf = 0; hf < 2; ++hf)
#pragma unroll
        for (int r = 0; r < 4; ++r) {
          const int irow = q0b + hf * 16 + (h << 2) + r;
          const int jc0 = j0 + ln, jc1 = jc0 + 16;
          if (!(jc0 <= irow && irow - jc0 < NWIN)) sS[hf][0][r] = MASKV;
          if (!(jc1 <= irow && irow - jc1 < NWIN)) sS[hf][1][r] = MASKV;
        }
    }

    // ---- online softmax: deferred-max fast path ----
    float ov = MASKV;
    float tmax[2][4];
#pragma unroll
    for (int hf = 0; hf < 2; ++hf)
#pragma unroll
      for (int r = 0; r < 4; ++r) {
        tmax[hf][r] = fmaxf(sS[hf][0][r], sS[hf][1][r]);
        ov = fmaxf(ov, tmax[hf][r] - m[hf][r]);
      }
    if (__any(ov > 8.0f)) {  // slow path: true row max + rescale
#pragma unroll
      for (int hf = 0; hf < 2; ++hf)
#pragma unroll
        for (int r = 0; r < 4; ++r) {
          float tm = tmax[hf][r];
          tm = fmaxf(tm, ROR(tm, 1));
          tm = fmaxf(tm, ROR(tm, 2));
          tm = fmaxf(tm, ROR(tm, 4));
          tm = fmaxf(tm, ROR(tm, 8));
          const float mn = fmaxf(m[hf][r], tm);
          const float co = ex2(m[hf][r] - mn);
          m[hf][r] = mn;
          lsum[hf][r] *= co;
#pragma unroll
          for (int db = 0; db < 8; ++db) Oc[hf][db][r] *= co;
        }
    }
#pragma unroll
    for (int hf = 0; hf < 2; ++hf)
#pragma unroll
      for (int r = 0; r < 4; ++r) {
        const float e0 = ex2(sS[hf][0][r] - m[hf][r]);
        const float e1 = ex2(sS[hf][1][r] - m[hf][r]);
        lsum[hf][r] += e0 + e1;  // per-lane partial; reduced in epilogue
        pw[(hf * 16 + (h << 2) + r) * 20 + ln] = cvtpk(e0, e1);
      }

    // ---- P V (pair-interleaved k-order on both operands) ----
    asm volatile("s_waitcnt lgkmcnt(0)" ::: "memory");
    const bf16x8 pa0 = *(const bf16x8*)(pw + (ln * 20 + (h << 2)));
    const bf16x8 pa1 = *(const bf16x8*)(pw + ((16 + ln) * 20 + (h << 2)));
    const unsigned int* VB = (const unsigned int*)Vb[cur];
    __builtin_amdgcn_s_setprio(1);
#pragma unroll
    for (int db = 0; db < 8; ++db) {
      const bf16x8 vv = *(const bf16x8*)(VB + ((((db << 4) + ln) << 4) + (h << 2)));
      Oc[0][db] = __builtin_amdgcn_mfma_f32_16x16x32_bf16(pa0, vv, Oc[0][db], 0, 0, 0);
      Oc[1][db] = __builtin_amdgcn_mfma_f32_16x16x32_bf16(pa1, vv, Oc[1][db], 0, 0, 0);
    }
    __builtin_amdgcn_s_setprio(0);
  }

  // ---- epilogue: reduce lsum across the 16 lanes of each row, write O ----
#pragma unroll
  for (int hf = 0; hf < 2; ++hf)
#pragma unroll
    for (int r = 0; r < 4; ++r) {
      float rs = lsum[hf][r];
      rs += ROR(rs, 1);
      rs += ROR(rs, 2);
      rs += ROR(rs, 4);
      rs += ROR(rs, 8);
      const float rl = 1.0f / rs;
      const int irow = q0b + hf * 16 + (h << 2) + r;
      float* op = out + ((size_t)(b << 11) + irow) * 4096 + (hk * 4 + g) * 128 + ln;
#pragma unroll
      for (int db = 0; db < 8; ++db) op[db * 16] = Oc[hf][db][r] * rl;
    }
}

extern "C" void kernel_launch(void* const* d_in, const int* in_sizes, int n_in,
                              void* d_out, int out_size, void* d_ws, size_t ws_size,
                              hipStream_t stream) {
  const float* q = (const float*)d_in[0];
  const float* k = (const float*)d_in[1];
  const float* v = (const float*)d_in[2];
  const int* pos = (const int*)d_in[3];
  float* out = (float*)d_out;

  const size_t TAB = (size_t)2048 * 128 * 4;        // 1MB cos/sin table
  const size_t KIMG = (size_t)16 * 64 * 8192;       // 8MB per image
  const size_t need = TAB + 2 * KIMG;

  if (ws_size >= need) {
    float* tab = (float*)d_ws;
    char* kimg = (char*)d_ws + TAB;
    char* vimg = kimg + KIMG;
    build_tab<<<2048, 64, 0, stream>>>(tab);
    prepass<<<1024, 256, 0, stream>>>(k, v, pos, tab,
                                      (unsigned short*)kimg, (unsigned int*)vimg);
    attn_fwd<true><<<1024, 256, 0, stream>>>(q, k, v, pos, kimg, vimg, out);
  } else {
    attn_fwd<false><<<1024, 256, 0, stream>>>(q, k, v, pos, nullptr, nullptr, out);
  }
}

// Round 4
// 94.145 us; speedup vs baseline: 2.0602x; 1.1941x over previous
//
#include <hip/hip_runtime.h>
#include <stdint.h>

#define NB 2
#define NS 2048
#define NHK 8
#define ND 128
#define NWIN 1024

using bf16x8 = __bf16 __attribute__((ext_vector_type(8)));
using f32x4  = float  __attribute__((ext_vector_type(4)));
using f32x2  = float  __attribute__((ext_vector_type(2)));
using f32x8  = float  __attribute__((ext_vector_type(8)));
using u16x8  = unsigned short __attribute__((ext_vector_type(8)));
using u32x4  = unsigned int   __attribute__((ext_vector_type(4)));

#define L2_10K (13.287712379549449f / 64.0f)  // log2(10000)/64
#define MASKV (-3.0e38f)

static __device__ __forceinline__ float ex2(float x) {
  return __builtin_amdgcn_exp2f(x);
}

static __device__ __forceinline__ unsigned short f2bf(float x) {
  unsigned int u = __builtin_bit_cast(unsigned int, x);
  u += 0x7FFFu + ((u >> 16) & 1u);
  return (unsigned short)(u >> 16);
}

// pack two f32 -> (bf16 lo, bf16 hi) in one u32
static __device__ __forceinline__ unsigned int cvtpk(float lo, float hi) {
  unsigned int r;
  asm("v_cvt_pk_bf16_f32 %0, %1, %2" : "=v"(r) : "v"(lo), "v"(hi));
  return r;
}

// async global->LDS, 16B per lane, LDS dest = uniform base + lane*16
static __device__ __forceinline__ void gll16(const void* g, void* l) {
  __builtin_amdgcn_global_load_lds(
      (const __attribute__((address_space(1))) void*)g,
      (__attribute__((address_space(3))) void*)l, 16, 0, 0);
}

// ---------------- cos/sin table: tab[p][0..63]=cos, [64..127]=sin ----------------
__global__ __launch_bounds__(64) void build_tab(float* __restrict__ tab) {
  const int p = blockIdx.x, f = threadIdx.x;
  float s, c;
  __sincosf((float)p * ex2(-(float)f * L2_10K), &s, &c);
  tab[(size_t)p * 128 + f] = c;
  tab[(size_t)p * 128 + 64 + f] = s;
}

// ---------------- prepass: per-tile K (roped, swizzled) and V ([d][key] swz) images ----
// grid 1024 = (b,hk,tile32), 8192B each per tile.
// K: unit u(0..511): row j=u>>4, 16B at ((u&15)*16 ^ ((j&7)<<4))
// V: dim d row of 64B = 4 sub-blocks of 8 keys; sub-block kp at slot (kp ^ ((d>>1)&3)),
//    8 bf16 = V[j0+8*kp+i][d], i ascending.
__global__ __launch_bounds__(256) void prepass(
    const float* __restrict__ kin, const float* __restrict__ vin,
    const int* __restrict__ pos, const float* __restrict__ tab,
    unsigned short* __restrict__ kimg, unsigned short* __restrict__ vimg) {
  const int bid = blockIdx.x;
  const int ti = bid & 63, gidx = bid >> 6;
  const int hk = gidx & 7, b = gidx >> 3;
  const int t = threadIdx.x;

  unsigned short* kout = kimg + (size_t)bid * 4096;
#pragma unroll
  for (int uu = 0; uu < 2; ++uu) {
    const int u = t * 2 + uu;
    const int j = u >> 4;
    const int d0 = ((u & 15) << 3) ^ ((j & 7) << 3);  // u16 index
    const int tok = (b << 11) + (ti << 5) + j;
    const float* kp = kin + (size_t)tok * (NHK * ND) + hk * ND;
    f32x8 a = *(const f32x8*)(kp + d0);
    f32x8 p = *(const f32x8*)(kp + (d0 ^ 64));
    const float* tr = tab + (size_t)(pos[tok] & 2047) * 128 + (d0 & 63);
    f32x8 c8 = *(const f32x8*)tr;
    f32x8 s8 = *(const f32x8*)(tr + 64);
    u16x8 o;
#pragma unroll
    for (int i = 0; i < 8; ++i) {
      float val = (d0 < 64) ? (a[i] * c8[i] - p[i] * s8[i])
                            : (a[i] * c8[i] + p[i] * s8[i]);
      o[i] = f2bf(val);
    }
    *(u16x8*)(kout + (size_t)u * 8) = o;
  }

  unsigned short* vout = vimg + (size_t)bid * 4096;
  {
    const int d0 = (t >> 2) << 1;     // even dim; thread covers d0, d0+1
    const int kp4 = t & 3;            // key sub-block (8 keys)
    const int tok0 = (b << 11) + (ti << 5) + (kp4 << 3);
    const float* vp = vin + (size_t)tok0 * (NHK * ND) + hk * ND + d0;
    u16x8 lo, hi;
#pragma unroll
    for (int i = 0; i < 8; ++i) {
      f32x2 r = *(const f32x2*)(vp + (size_t)i * (NHK * ND));
      lo[i] = f2bf(r[0]);
      hi[i] = f2bf(r[1]);
    }
    const int sub = kp4 ^ ((d0 >> 1) & 3);  // same for d0 and d0+1
    *(u16x8*)(vout + d0 * 32 + sub * 8) = lo;
    *(u16x8*)(vout + (d0 + 1) * 32 + sub * 8) = hi;
  }
}

// ---------------- fused flash attention (swapped QK^T, in-register P) ----------------
// 256 thr = 4 waves (one per g). Wave owns 32 q-rows (2 halves of 16) x D=128.
// KV tiles of 32; double-buffered LDS via global_load_lds from images.
// S^T = mfma(K, Q): lane(h,ln): q-row = qh*16+ln, keys ki*16 + h*4 + r.
// PV A-frag assembled in-register via cvt_pk + permlane{32,16}_swap.
template <bool PRE>
__global__ __launch_bounds__(256, 3) void attn_fwd(
    const float* __restrict__ qin, const float* __restrict__ kin,
    const float* __restrict__ vin, const int* __restrict__ pos,
    const char* __restrict__ kimg, const char* __restrict__ vimg,
    float* __restrict__ out) {
  __shared__ __align__(16) char Kb[2][8192];
  __shared__ __align__(16) char Vb[2][8192];

  const int B = blockIdx.x;
  // XCD swizzle: all 64 q-tiles of a (b,hk) group land on one XCD; heavy tiles first
  const int group = (B & 7) + ((B >> 9) << 3);
  const int qt = 63 - ((B >> 3) & 63);
  const int hk = group & 7, b = group >> 3;

  const int tid = threadIdx.x;
  const int w = tid >> 6, lane = tid & 63, h = lane >> 4, ln = lane & 15;
  const int g = w;
  const int q0b = qt << 5;
  int lo = q0b - (NWIN - 1);
  if (lo < 0) lo = 0;
  lo &= ~31;
  const int ti0 = lo >> 5;
  const int nt = (q0b >> 5) - ti0 + 1;

  const size_t gbase = (size_t)group * 64 * 8192;
  const char* kg = PRE ? kimg + gbase + (size_t)(w * 128 + lane) * 16 : nullptr;
  const char* vg = PRE ? vimg + gbase + (size_t)(w * 128 + lane) * 16 : nullptr;

  auto stage = [&](int cur, int ti) {
    if constexpr (PRE) {
      const char* ks = kg + (size_t)ti * 8192;
      const char* vs = vg + (size_t)ti * 8192;
      char* kd = &Kb[cur][w * 2048];
      char* vd = &Vb[cur][w * 2048];
      gll16(ks, kd);
      gll16(ks + 1024, kd + 1024);
      gll16(vs, vd);
      gll16(vs + 1024, vd + 1024);
    } else {
      // K: rope inline, swizzled writes
      const int j = tid >> 3;
      const int du = (tid & 7) << 4;
      const int tok = (b << 11) + (ti << 5) + j;
      const float* kp = kin + (size_t)tok * (NHK * ND) + hk * ND;
      const float pj = (float)pos[tok];
#pragma unroll
      for (int gq = 0; gq < 2; ++gq) {
        const int dd = du + gq * 8;
        f32x8 a = *(const f32x8*)(kp + dd);
        f32x8 p = *(const f32x8*)(kp + (dd ^ 64));
        u16x8 o;
#pragma unroll
        for (int i = 0; i < 8; ++i) {
          float s, c;
          __sincosf(pj * ex2(-(float)((dd & 63) + i) * L2_10K), &s, &c);
          float val = (dd < 64) ? (a[i] * c - p[i] * s) : (a[i] * c + p[i] * s);
          o[i] = f2bf(val);
        }
        *(u16x8*)(&Kb[cur][((j << 8) + (dd << 1)) ^ ((j & 7) << 4)]) = o;
      }
      // V: [d][key] with sub-block swizzle
      const int d0 = (tid >> 2) << 1;
      const int kp4 = tid & 3;
      const float* vp = vin + (size_t)((b << 11) + (ti << 5) + (kp4 << 3)) * (NHK * ND) + hk * ND + d0;
      u16x8 lov, hiv;
#pragma unroll
      for (int i = 0; i < 8; ++i) {
        f32x2 r = *(const f32x2*)(vp + (size_t)i * (NHK * ND));
        lov[i] = f2bf(r[0]);
        hiv[i] = f2bf(r[1]);
      }
      const int sub = kp4 ^ ((d0 >> 1) & 3);
      unsigned short* vb16 = (unsigned short*)Vb[cur];
      *(u16x8*)(vb16 + d0 * 32 + sub * 8) = lov;
      *(u16x8*)(vb16 + (d0 + 1) * 32 + sub * 8) = hiv;
    }
  };

  // prologue: stage tile 0 into buf0 (overlaps Q rope)
  stage(0, ti0);

  // ---- Q fragments: rope + scale*log2e, bf16 (B-operand: col=ln=q, k=h*8+i) ----
  const float QSC = 0.08838834764831845f * 1.4426950408889634f;
  bf16x8 qfr[2][4];
#pragma unroll
  for (int hf = 0; hf < 2; ++hf) {
    const int qrow = q0b + hf * 16 + ln;
    const size_t tokq = (size_t)(b << 11) + qrow;
    const float* qp = qin + tokq * 4096 + (hk * 4 + g) * 128;
    const float posq = (float)pos[tokq];
    const int r0 = h << 3;
    const int r1 = 32 + (h << 3);
    f32x8 a0 = *(const f32x8*)(qp + r0);
    f32x8 a1 = *(const f32x8*)(qp + r1);
    f32x8 a2 = *(const f32x8*)(qp + r0 + 64);
    f32x8 a3 = *(const f32x8*)(qp + r1 + 64);
    u16x8 u0, u1, u2, u3;
#pragma unroll
    for (int i = 0; i < 8; ++i) {
      float c0, s0, c1, s1;
      __sincosf(posq * ex2(-(float)(r0 + i) * L2_10K), &s0, &c0);
      __sincosf(posq * ex2(-(float)(r1 + i) * L2_10K), &s1, &c1);
      u0[i] = f2bf((a0[i] * c0 - a2[i] * s0) * QSC);
      u1[i] = f2bf((a1[i] * c1 - a3[i] * s1) * QSC);
      u2[i] = f2bf((a2[i] * c0 + a0[i] * s0) * QSC);
      u3[i] = f2bf((a3[i] * c1 + a1[i] * s1) * QSC);
    }
    qfr[hf][0] = __builtin_bit_cast(bf16x8, u0);
    qfr[hf][1] = __builtin_bit_cast(bf16x8, u1);
    qfr[hf][2] = __builtin_bit_cast(bf16x8, u2);
    qfr[hf][3] = __builtin_bit_cast(bf16x8, u3);
  }

  f32x4 Oc[2][8] = {};
  float msh[2] = {-1e30f, -1e30f};   // running max per q-row (q = qh*16+ln), replicated over h
  float lsum[2] = {};                // per-lane partial sum (this lane's key slice)
  const int sw = (ln & 7) << 4;
  const int vsub = (h ^ ((ln >> 1) & 3)) << 4;

  for (int t = 0; t < nt; ++t) {
    const int cur = t & 1;
    asm volatile("s_waitcnt vmcnt(0)" ::: "memory");
    __syncthreads();  // tile-t data resident; prev reads of buf[cur^1] done
    if (t + 1 < nt) stage(cur ^ 1, ti0 + t + 1);

    const int j0 = (ti0 + t) << 5;
    const char* KB = Kb[cur];

    // ---- S^T = K Q^T: D[key][q], 2 key sub-tiles x 2 q halves ----
    f32x4 sT[2][2] = {};  // [qh][ki]
    __builtin_amdgcn_s_setprio(1);
#pragma unroll
    for (int c = 0; c < 4; ++c) {
      const bf16x8 k0 = *(const bf16x8*)(
          KB + (((ln << 8) + (c << 6) + (h << 4)) ^ sw));
      const bf16x8 k1 = *(const bf16x8*)(
          KB + ((((16 + ln) << 8) + (c << 6) + (h << 4)) ^ sw));
      sT[0][0] = __builtin_amdgcn_mfma_f32_16x16x32_bf16(k0, qfr[0][c], sT[0][0], 0, 0, 0);
      sT[0][1] = __builtin_amdgcn_mfma_f32_16x16x32_bf16(k1, qfr[0][c], sT[0][1], 0, 0, 0);
      sT[1][0] = __builtin_amdgcn_mfma_f32_16x16x32_bf16(k0, qfr[1][c], sT[1][0], 0, 0, 0);
      sT[1][1] = __builtin_amdgcn_mfma_f32_16x16x32_bf16(k1, qfr[1][c], sT[1][1], 0, 0, 0);
    }
    __builtin_amdgcn_s_setprio(0);

    // ---- mask only boundary tiles (wave-uniform branch) ----
    if ((j0 >= q0b) || (j0 < q0b - 992)) {
#pragma unroll
      for (int qh = 0; qh < 2; ++qh) {
        const int irow = q0b + qh * 16 + ln;
#pragma unroll
        for (int ki = 0; ki < 2; ++ki)
#pragma unroll
          for (int r = 0; r < 4; ++r) {
            const int j = j0 + ki * 16 + (h << 2) + r;
            if (!(j <= irow && irow - j < NWIN)) sT[qh][ki][r] = MASKV;
          }
      }
    }

    // ---- online softmax: deferred-max fast path (pure per-lane) ----
    float pm[2];
#pragma unroll
    for (int qh = 0; qh < 2; ++qh) {
      const f32x4 s0 = sT[qh][0], s1 = sT[qh][1];
      pm[qh] = fmaxf(fmaxf(fmaxf(s0[0], s0[1]), fmaxf(s0[2], s0[3])),
                     fmaxf(fmaxf(s1[0], s1[1]), fmaxf(s1[2], s1[3])));
    }
    const float ov = fmaxf(pm[0] - msh[0], pm[1] - msh[1]);
    if (__any(ov > 8.0f)) {  // slow path: true row max + rescale
#pragma unroll
      for (int qh = 0; qh < 2; ++qh) {
        float M = pm[qh];
        M = fmaxf(M, __shfl_xor(M, 16));
        M = fmaxf(M, __shfl_xor(M, 32));
        const float mn = fmaxf(msh[qh], M);
        const float co = ex2(msh[qh] - mn);  // replicated across h-groups
        msh[qh] = mn;
        lsum[qh] *= co;
        float coO[4];
#pragma unroll
        for (int r = 0; r < 4; ++r) coO[r] = __shfl(co, (h << 2) + r);
#pragma unroll
        for (int db = 0; db < 8; ++db)
#pragma unroll
          for (int r = 0; r < 4; ++r) Oc[qh][db][r] *= coO[r];
      }
    }

    bf16x8 pa[2];
#pragma unroll
    for (int qh = 0; qh < 2; ++qh) {
      float e[2][4];
#pragma unroll
      for (int ki = 0; ki < 2; ++ki)
#pragma unroll
        for (int r = 0; r < 4; ++r) e[ki][r] = ex2(sT[qh][ki][r] - msh[qh]);
      lsum[qh] += ((e[0][0] + e[0][1]) + (e[0][2] + e[0][3])) +
                  ((e[1][0] + e[1][1]) + (e[1][2] + e[1][3]));
      unsigned int A = cvtpk(e[0][0], e[0][1]);
      unsigned int Bk = cvtpk(e[0][2], e[0][3]);
      unsigned int C = cvtpk(e[1][0], e[1][1]);
      unsigned int D = cvtpk(e[1][2], e[1][3]);
      // redistribute: group h ends with keys 8h..8h+7 in k-order
      asm volatile("v_permlane32_swap_b32 %0, %1" : "+v"(A), "+v"(C));
      asm volatile("v_permlane16_swap_b32 %0, %1" : "+v"(A), "+v"(C));
      asm volatile("v_permlane32_swap_b32 %0, %1" : "+v"(Bk), "+v"(D));
      asm volatile("v_permlane16_swap_b32 %0, %1" : "+v"(Bk), "+v"(D));
      u32x4 pk4 = {A, Bk, C, D};
      pa[qh] = __builtin_bit_cast(bf16x8, pk4);
    }

    // ---- P V: O[q][d] += P[q][keys] V[keys][d] ----
    const char* VB = Vb[cur];
    __builtin_amdgcn_s_setprio(1);
#pragma unroll
    for (int db = 0; db < 8; ++db) {
      const bf16x8 vv = *(const bf16x8*)(VB + (db << 10) + (ln << 6) + vsub);
      Oc[0][db] = __builtin_amdgcn_mfma_f32_16x16x32_bf16(pa[0], vv, Oc[0][db], 0, 0, 0);
      Oc[1][db] = __builtin_amdgcn_mfma_f32_16x16x32_bf16(pa[1], vv, Oc[1][db], 0, 0, 0);
    }
    __builtin_amdgcn_s_setprio(0);
  }

  // ---- epilogue: full row-sum, redistribute to O view, write ----
#pragma unroll
  for (int qh = 0; qh < 2; ++qh) {
    float ls = lsum[qh];
    ls += __shfl_xor(ls, 16);
    ls += __shfl_xor(ls, 32);
#pragma unroll
    for (int r = 0; r < 4; ++r) {
      const float rl = 1.0f / __shfl(ls, (h << 2) + r);
      const int irow = q0b + qh * 16 + (h << 2) + r;
      float* op = out + ((size_t)(b << 11) + irow) * 4096 + (hk * 4 + g) * 128 + ln;
#pragma unroll
      for (int db = 0; db < 8; ++db) op[db * 16] = Oc[qh][db][r] * rl;
    }
  }
}

extern "C" void kernel_launch(void* const* d_in, const int* in_sizes, int n_in,
                              void* d_out, int out_size, void* d_ws, size_t ws_size,
                              hipStream_t stream) {
  const float* q = (const float*)d_in[0];
  const float* k = (const float*)d_in[1];
  const float* v = (const float*)d_in[2];
  const int* pos = (const int*)d_in[3];
  float* out = (float*)d_out;

  const size_t TAB = (size_t)2048 * 128 * 4;        // 1MB cos/sin table
  const size_t KIMG = (size_t)16 * 64 * 8192;       // 8MB per image
  const size_t need = TAB + 2 * KIMG;

  if (ws_size >= need) {
    float* tab = (float*)d_ws;
    char* kimg = (char*)d_ws + TAB;
    char* vimg = kimg + KIMG;
    build_tab<<<2048, 64, 0, stream>>>(tab);
    prepass<<<1024, 256, 0, stream>>>(k, v, pos, tab,
                                      (unsigned short*)kimg, (unsigned short*)vimg);
    attn_fwd<true><<<1024, 256, 0, stream>>>(q, k, v, pos, kimg, vimg, out);
  } else {
    attn_fwd<false><<<1024, 256, 0, stream>>>(q, k, v, pos, nullptr, nullptr, out);
  }
}